// Round 7
// baseline (235.241 us; speedup 1.0000x reference)
//
#include <hip/hip_runtime.h>
#include <cstdint>
#include <cstddef>

typedef __bf16 bf16;
typedef __bf16 bf16x4 __attribute__((ext_vector_type(4)));
typedef __bf16 bf16x8 __attribute__((ext_vector_type(8)));
typedef float  f32x4  __attribute__((ext_vector_type(4)));

#define BATCH 4
#define SEQ   2048
#define DIM   1024
#define LDP   2112   // padded leading dim for P and Vt

// RNE float -> bf16
__device__ __forceinline__ bf16 to_bf16(float f) {
    unsigned u = __builtin_bit_cast(unsigned, f);
    u += 0x7fffu + ((u >> 16) & 1u);
    unsigned short h = (unsigned short)(u >> 16);
    return __builtin_bit_cast(bf16, h);
}

// async global->LDS, 16B per lane. LDS base must be wave-uniform; HW adds lane*16.
__device__ __forceinline__ void load16_lds(const bf16* g, bf16* l) {
    __builtin_amdgcn_global_load_lds(
        (__attribute__((address_space(1))) void*)(g),
        (__attribute__((address_space(3))) void*)(l),
        16, 0, 0);
}

#define BARRIER() do { asm volatile("" ::: "memory"); \
                       __builtin_amdgcn_s_barrier();  \
                       asm volatile("" ::: "memory"); } while (0)
#define LGKM0()   asm volatile("s_waitcnt lgkmcnt(0)" ::: "memory")
#define VM0()     asm volatile("s_waitcnt vmcnt(0)" ::: "memory")

// ---------------------------------------------------------------------------
// Big-phase 256x256 core (BK=64), 512 threads = 8 waves (2Mx4N), 128 KB LDS,
// 1 block/CU. ONE barrier per K-tile (r4). Used by proj_qk / scores (control
// kernels this round).
// Chunk swizzle: LDS[row][p] = global[row][p ^ (row&7)] via pre-swizzled
// global source; readers use pk = (c ^ (row&7))*8. Conflicts = 0 (r2).
// r6: XCD-rect block swizzle cut pv FETCH 139.5->32.9 MB but time barely
// moved -> stall is sync-structure at 1 block/CU (no TLP), not traffic.
// ---------------------------------------------------------------------------

// stage one half-tile: 128 rows x 64 k of one matrix (2 gload_lds / thread).
__device__ __forceinline__ void stage_half(
    const bf16* __restrict__ srcRow0, int ld, int k0, bf16* dstHalfBase)
{
    const int tid  = threadIdx.x;
    const int wave = tid >> 6;
    const int lane = tid & 63;
    const int rg   = lane >> 3;                 // row within 8-row group
    const int scoff = ((lane & 7) ^ rg) * 8;    // pre-swizzled global chunk
#pragma unroll
    for (int j = 0; j < 2; ++j) {
        const int r = wave * 16 + j * 8;        // wave-uniform LDS row base
        load16_lds(srcRow0 + (size_t)(r + rg) * ld + k0 + scoff,
                   dstHalfBase + r * 64);
    }
}

// ---- 256x256 tile, waves 2M x 4N, per-wave 128x64, acc[8][4] -----------
__device__ __forceinline__ void gemm_big_core(
    const bf16* __restrict__ Ablk, const bf16* __restrict__ Bblk,
    int K, int lda, int ldb, bf16* As, bf16* Bs, f32x4 acc[8][4])
{
    const int tid  = threadIdx.x;
    const int lane = tid & 63;
    const int wave = tid >> 6;
    const int wr   = wave >> 2;          // 0..1 (M)
    const int wc   = wave & 3;           // 0..3 (N)
    const int r16  = lane & 15;
    const int g    = lane >> 4;
    const int r7   = r16 & 7;
    const int pk0  = ((g) ^ r7) * 8;         // phys chunk offset, ks=0
    const int pk1  = ((4 + g) ^ r7) * 8;     // ks=1
    const int arow = (wr * 128 + r16) * 64;
    const int brow = (wc * 64 + r16) * 64;
    const int NT   = K >> 6;

    // prologue: stage tile 0 into buffer 0
    stage_half(Bblk, ldb, 0, Bs);
    stage_half(Bblk + (size_t)128 * ldb, ldb, 0, Bs + 8192);
    stage_half(Ablk, lda, 0, As);
    stage_half(Ablk + (size_t)128 * lda, lda, 0, As + 8192);
    VM0();
    BARRIER();

#pragma unroll 2
    for (int t = 0; t < NT; ++t) {
        bf16* Ac = As + (t & 1) * 16384;
        bf16* Bc = Bs + (t & 1) * 16384;
        bf16* An = As + ((t + 1) & 1) * 16384;
        bf16* Bn = Bs + ((t + 1) & 1) * 16384;
        const int k1 = (t + 1) << 6;

        bf16x8 b[4][2], a[4][2], a2[4][2];
#pragma unroll
        for (int n = 0; n < 4; ++n) {
            b[n][0] = *(const bf16x8*)(Bc + brow + n * 1024 + pk0);
            b[n][1] = *(const bf16x8*)(Bc + brow + n * 1024 + pk1);
        }
#pragma unroll
        for (int m = 0; m < 4; ++m) {
            a[m][0] = *(const bf16x8*)(Ac + arow + m * 1024 + pk0);
            a[m][1] = *(const bf16x8*)(Ac + arow + m * 1024 + pk1);
        }
        if (t + 1 < NT) {
            stage_half(Bblk, ldb, k1, Bn);
            stage_half(Bblk + (size_t)128 * ldb, ldb, k1, Bn + 8192);
            stage_half(Ablk, lda, k1, An);
            stage_half(Ablk + (size_t)128 * lda, lda, k1, An + 8192);
        }
#pragma unroll
        for (int m = 0; m < 4; ++m)
#pragma unroll
            for (int n = 0; n < 4; ++n)
#pragma unroll
                for (int ks = 0; ks < 2; ++ks)
                    acc[m][n] = __builtin_amdgcn_mfma_f32_16x16x32_bf16(
                        a[m][ks], b[n][ks], acc[m][n], 0, 0, 0);
#pragma unroll
        for (int m = 0; m < 4; ++m) {
            a2[m][0] = *(const bf16x8*)(Ac + arow + 4096 + m * 1024 + pk0);
            a2[m][1] = *(const bf16x8*)(Ac + arow + 4096 + m * 1024 + pk1);
        }
#pragma unroll
        for (int m = 0; m < 4; ++m)
#pragma unroll
            for (int n = 0; n < 4; ++n)
#pragma unroll
                for (int ks = 0; ks < 2; ++ks)
                    acc[4 + m][n] = __builtin_amdgcn_mfma_f32_16x16x32_bf16(
                        a2[m][ks], b[n][ks], acc[4 + m][n], 0, 0, 0);

        LGKM0();
        if (t + 1 < NT) VM0();
        BARRIER();
    }
}

// ---------------------------------------------------------------------------
// Small core (r7): 128x128 tile, BK=32, dbuf, 256 threads = 4 waves (2Mx2N),
// per-wave 64x64, acc[4][4]. LDS = 2x(128+128)x32x2B = 32 KB -> with a
// 512-block grid, 2 blocks co-resident per CU. Mechanism: each SIMD hosts one
// wave from each of two INDEPENDENTLY-synchronized blocks; when block A waits
// at its barrier/vmcnt, block B's wave issues MFMAs (m97-style implicit TLP
// that the 1-block/CU big cores cannot have).
// Swizzle for 4-chunk (64 B) rows: phys chunk p = c ^ ((row>>1)&3), applied
// to the global source (LDS dest linear) and to the ds_read address. Bank
// check: 64-lane b128 read -> 8 lanes per 4-bank span, distinct slots,
// conflict-free (2 lanes/16B-slot from row parity = free broadcast pair).
// ---------------------------------------------------------------------------

// stage 64 rows x 32 k (4 KB): 1 gload_lds / thread, 256 threads.
__device__ __forceinline__ void stage_q32(
    const bf16* __restrict__ srcRow0, int ld, int k0, bf16* dstBase)
{
    const int t  = threadIdx.x;                 // 0..255
    const int rl = t >> 2;                      // local row 0..63
    const int c  = (t & 3) ^ ((rl >> 1) & 3);   // pre-swizzled k-chunk
    load16_lds(srcRow0 + (size_t)rl * ld + k0 + c * 8,
               dstBase + (t >> 6) * 512);       // wave-uniform base
}

__device__ __forceinline__ void gemm_sm_core(
    const bf16* __restrict__ Ablk, const bf16* __restrict__ Bblk,
    int K, int lda, int ldb, bf16* As, bf16* Bs, f32x4 acc[4][4])
{
    const int tid  = threadIdx.x;
    const int lane = tid & 63;
    const int wave = tid >> 6;
    const int wr   = wave >> 1;          // 0..1 (M)
    const int wc   = wave & 1;           // 0..1 (N)
    const int r16  = lane & 15;
    const int g    = lane >> 4;
    const int pk   = (g ^ ((r16 >> 1) & 3)) * 8;   // phys chunk offset
    const int arow = (wr * 64 + r16) * 32;
    const int brow = (wc * 64 + r16) * 32;
    const int NT   = K >> 5;

    // prologue: stage tile 0 into buffer 0
    stage_q32(Ablk, lda, 0, As);
    stage_q32(Ablk + (size_t)64 * lda, lda, 0, As + 2048);
    stage_q32(Bblk, ldb, 0, Bs);
    stage_q32(Bblk + (size_t)64 * ldb, ldb, 0, Bs + 2048);
    VM0();
    BARRIER();

#pragma unroll 2
    for (int t = 0; t < NT; ++t) {
        bf16* Ac = As + (t & 1) * 4096;
        bf16* Bc = Bs + (t & 1) * 4096;
        bf16* An = As + ((t + 1) & 1) * 4096;
        bf16* Bn = Bs + ((t + 1) & 1) * 4096;
        const int k1 = (t + 1) << 5;

        bf16x8 a[4], b[4];
#pragma unroll
        for (int n = 0; n < 4; ++n)
            b[n] = *(const bf16x8*)(Bc + brow + n * 512 + pk);
#pragma unroll
        for (int m = 0; m < 4; ++m)
            a[m] = *(const bf16x8*)(Ac + arow + m * 512 + pk);
        if (t + 1 < NT) {
            stage_q32(Ablk, lda, k1, An);
            stage_q32(Ablk + (size_t)64 * lda, lda, k1, An + 2048);
            stage_q32(Bblk, ldb, k1, Bn);
            stage_q32(Bblk + (size_t)64 * ldb, ldb, k1, Bn + 2048);
        }
#pragma unroll
        for (int m = 0; m < 4; ++m)
#pragma unroll
            for (int n = 0; n < 4; ++n)
                acc[m][n] = __builtin_amdgcn_mfma_f32_16x16x32_bf16(
                    a[m], b[n], acc[m][n], 0, 0, 0);

        LGKM0();
        if (t + 1 < NT) VM0();
        BARRIER();
    }
}

// shared bf16 C-writer for the 256^2 core
__device__ __forceinline__ void write_c256(
    bf16* __restrict__ Cb, int ldc, const f32x4 acc[8][4])
{
    const int lane = threadIdx.x & 63;
    const int wave = threadIdx.x >> 6;
    const int wr = wave >> 2, wc = wave & 3;
    const int r16 = lane & 15, g = lane >> 4;
    const int row0 = wr * 128 + g * 4;
    const int col0 = wc * 64 + r16;
#pragma unroll
    for (int m = 0; m < 8; ++m)
#pragma unroll
        for (int n = 0; n < 4; ++n)
#pragma unroll
            for (int rr = 0; rr < 4; ++rr)
                Cb[(size_t)(row0 + m * 16 + rr) * ldc + col0 + n * 16] =
                    to_bf16(acc[m][n][rr]);
}

// ---------------------------------------------------------------------------
// proj_qk (256^2 core): 256 blocks -> Q,K = X @ W{q,k}T^T. XCD-rect swizzle.
// ---------------------------------------------------------------------------
__global__ __launch_bounds__(512, 2) void proj_qk(
    const bf16* __restrict__ xb, const bf16* __restrict__ Wt,
    bf16* __restrict__ Q, bf16* __restrict__ Kb)
{
    __shared__ bf16 As[32768];
    __shared__ bf16 Bs[32768];
    f32x4 acc[8][4] = {};

    const int p = blockIdx.x;
    const int x = p & 7, s = p >> 3;
    const int my = x * 4 + (s >> 3);
    const int j  = s & 7;
    const bf16* Ab = xb + (size_t)my * 256 * DIM;
    const bf16* Bb = Wt + (size_t)((j >> 2) ? DIM * DIM : 0)
                        + (size_t)(j & 3) * 256 * DIM;
    bf16* dst = (j >> 2) ? Kb : Q;
    bf16* Cb = dst + (size_t)my * 256 * DIM + (size_t)(j & 3) * 256;

    gemm_big_core(Ab, Bb, DIM, DIM, DIM, As, Bs, acc);
    write_c256(Cb, DIM, acc);
}

// ---------------------------------------------------------------------------
// proj_v (small core): 512 blocks -> Vt[b] = WvT @ X[b]^T, 128x128 tiles,
// 2 blocks/CU. XCD swizzle: bz = x&3, vx-half by x>>2 -> xb panels XCD-local.
// ---------------------------------------------------------------------------
__global__ __launch_bounds__(256, 2) void proj_v(
    const bf16* __restrict__ xb, const bf16* __restrict__ Wt,
    bf16* __restrict__ Vt)
{
    __shared__ bf16 As[8192];
    __shared__ bf16 Bs[8192];
    f32x4 acc[4][4] = {};

    const int p = blockIdx.x;
    const int x = p & 7, s = p >> 3;
    const int bz = x & 3;
    const int vx = (x >> 2) * 8 + (s & 7);   // 0..15 (128-col groups of Vt)
    const int vy = s >> 3;                   // 0..7  (128-row groups of Vt)
    const bf16* Ab = Wt + (size_t)2 * DIM * DIM + (size_t)vy * 128 * DIM;
    const bf16* Bb = xb + (size_t)bz * SEQ * DIM + (size_t)vx * 128 * DIM;
    bf16* Cb = Vt + (size_t)bz * DIM * LDP + (size_t)vy * 128 * LDP
                  + (size_t)vx * 128;

    gemm_sm_core(Ab, Bb, DIM, DIM, DIM, As, Bs, acc);

    const int lane = threadIdx.x & 63;
    const int wave = threadIdx.x >> 6;
    const int wr = wave >> 1, wc = wave & 1;
    const int r16 = lane & 15, g = lane >> 4;
    const int row0 = wr * 64 + g * 4;
    const int col0 = wc * 64 + r16;
#pragma unroll
    for (int m = 0; m < 4; ++m)
#pragma unroll
        for (int n = 0; n < 4; ++n)
#pragma unroll
            for (int rr = 0; rr < 4; ++rr)
                Cb[(size_t)(row0 + m * 16 + rr) * LDP + col0 + n * 16] =
                    to_bf16(acc[m][n][rr]);
}

// ---------------------------------------------------------------------------
// scores (256^2 core): P' = exp((Q @ K^T)/32) (bf16, ldc=LDP), fp32 row sums
// via atomics. 256 blocks, XCD-rect swizzle.
// ---------------------------------------------------------------------------
__global__ __launch_bounds__(512, 2) void gemm_scores8(
    const bf16* __restrict__ Qm, const bf16* __restrict__ Kb,
    bf16* __restrict__ P, float* __restrict__ lsum)
{
    __shared__ bf16 As[32768];
    __shared__ bf16 Bs[32768];
    f32x4 acc[8][4] = {};

    const int p = blockIdx.x;
    const int x = p & 7, s = p >> 3;
    const int bz = x & 3;
    const int by = (x >> 2) * 4 + (s >> 3);
    const int bx = s & 7;
    const bf16* Ab = Qm + (size_t)bz * SEQ * DIM + (size_t)by * 256 * DIM;
    const bf16* Bb = Kb + (size_t)bz * SEQ * DIM + (size_t)bx * 256 * DIM;
    gemm_big_core(Ab, Bb, DIM, DIM, DIM, As, Bs, acc);

    bf16* Cb  = P + (size_t)bz * SEQ * LDP;
    float* ls = lsum + (size_t)bz * SEQ;
    const int lane = threadIdx.x & 63;
    const int wave = threadIdx.x >> 6;
    const int wr = wave >> 2, wc = wave & 3;
    const int r16 = lane & 15, g = lane >> 4;
    const int rowB = by * 256 + wr * 128 + g * 4;
    const int colB = bx * 256 + wc * 64 + r16;
#pragma unroll
    for (int m = 0; m < 8; ++m)
#pragma unroll
        for (int rr = 0; rr < 4; ++rr) {
            float sum = 0.0f;
#pragma unroll
            for (int n = 0; n < 4; ++n) {
                const float e = __expf(acc[m][n][rr] * 0.03125f);
                sum += e;
                Cb[(size_t)(rowB + m * 16 + rr) * LDP + colB + n * 16] = to_bf16(e);
            }
            sum += __shfl_xor(sum, 1);
            sum += __shfl_xor(sum, 2);
            sum += __shfl_xor(sum, 4);
            sum += __shfl_xor(sum, 8);
            if (r16 == 0)
                atomicAdd(ls + rowB + m * 16 + rr, sum);
        }
}

// ---------------------------------------------------------------------------
// PV (small core): out = (P' @ Vt^T) / l, fp32. 512 blocks (16 by x 8 bx x
// 4 bz), 128x128 tiles, K = SEQ (NT=64), 2 blocks/CU. XCD swizzle keeps P
// panels XCD-exclusive.
// ---------------------------------------------------------------------------
__global__ __launch_bounds__(256, 2) void gemm_pv_sm(
    const bf16* __restrict__ P, const bf16* __restrict__ Vt,
    float* __restrict__ C, const float* __restrict__ lsum)
{
    __shared__ bf16 As[8192];
    __shared__ bf16 Bs[8192];
    f32x4 acc[4][4] = {};

    const int p = blockIdx.x;
    const int x = p & 7, s = p >> 3;
    const int bz = x & 3;
    const int by = (x >> 2) * 8 + (s >> 3);  // 0..15 (128-row P panels)
    const int bx = s & 7;                    // 0..7  (128-col out panels)
    const bf16* Ab = P  + (size_t)bz * SEQ * LDP + (size_t)by * 128 * LDP;
    const bf16* Bb = Vt + (size_t)bz * DIM * LDP + (size_t)bx * 128 * LDP;
    gemm_sm_core(Ab, Bb, SEQ, LDP, LDP, As, Bs, acc);

    float* Cb = C + (size_t)bz * SEQ * DIM;
    const float* ls = lsum + (size_t)bz * SEQ;
    const int lane = threadIdx.x & 63;
    const int wave = threadIdx.x >> 6;
    const int wr = wave >> 1, wc = wave & 1;
    const int r16 = lane & 15, g = lane >> 4;
    const int row0 = by * 128 + wr * 64 + g * 4;
    const int col0 = bx * 128 + wc * 64 + r16;
#pragma unroll
    for (int m = 0; m < 4; ++m)
#pragma unroll
        for (int rr = 0; rr < 4; ++rr) {
            const int row = row0 + m * 16 + rr;
            const float inv = __builtin_amdgcn_rcpf(ls[row]);
#pragma unroll
            for (int n = 0; n < 4; ++n)
                Cb[(size_t)row * DIM + col0 + n * 16] = acc[m][n][rr] * inv;
        }
}

// ---------------------------------------------------------------------------
// Fused prep: blocks [0,8192) cast x fp32->bf16; blocks [8192,11264) transpose
// + cast weights; block 11264 zeroes lsum. All branches block-uniform.
// ---------------------------------------------------------------------------
__global__ __launch_bounds__(256) void prep(
    const float* __restrict__ x,  const float* __restrict__ wq,
    const float* __restrict__ wk, const float* __restrict__ wv,
    bf16* __restrict__ xb, bf16* __restrict__ Wt, float* __restrict__ lsum)
{
    __shared__ float tile[32][33];
    const int b = blockIdx.x;
    const int tid = threadIdx.x;
    if (b < 8192) {
        const size_t i = ((size_t)b * 256 + tid) * 4;
        const float4 v = *(const float4*)(x + i);
        bf16x4 o = { to_bf16(v.x), to_bf16(v.y), to_bf16(v.z), to_bf16(v.w) };
        *(bf16x4*)(xb + i) = o;
    } else if (b < 8192 + 3072) {
        const int t   = b - 8192;
        const int sel = t >> 10;
        const int n0  = (t & 31) * 32;
        const int k0  = ((t >> 5) & 31) * 32;
        const float* w = (sel == 0) ? wq : (sel == 1) ? wk : wv;
        const int tx = tid & 31, ty = tid >> 5;
#pragma unroll
        for (int j = 0; j < 32; j += 8)
            tile[ty + j][tx] = w[(size_t)(k0 + ty + j) * 1024 + n0 + tx];
        __syncthreads();
        bf16* dst = Wt + (size_t)sel * 1024 * 1024;
#pragma unroll
        for (int j = 0; j < 32; j += 8)
            dst[(size_t)(n0 + ty + j) * 1024 + k0 + tx] = to_bf16(tile[tx][ty + j]);
    } else {
#pragma unroll
        for (int i = 0; i < 32; ++i)
            lsum[i * 256 + tid] = 0.0f;
    }
}

// ---------------------------------------------------------------------------
extern "C" void kernel_launch(void* const* d_in, const int* in_sizes, int n_in,
                              void* d_out, int out_size, void* d_ws, size_t ws_size,
                              hipStream_t stream)
{
    const float* x  = (const float*)d_in[0];
    const float* wq = (const float*)d_in[1];
    const float* wk = (const float*)d_in[2];
    const float* wv = (const float*)d_in[3];
    float* out = (float*)d_out;
    char* ws = (char*)d_ws;

    // workspace layout (bytes)
    bf16*  xb   = (bf16*)(ws);                   // 16 MB [8192,1024]
    bf16*  Wt   = (bf16*)(ws + (16u << 20));     //  6 MB [3072,1024] (WqT|WkT|WvT)
    bf16*  Q    = (bf16*)(ws + (22u << 20));     // 16 MB [8192,1024]
    bf16*  Kb   = (bf16*)(ws + (38u << 20));     // 16 MB [8192,1024]
    bf16*  Vt   = (bf16*)(ws + (54u << 20));     // 17 MB [4][1024][LDP]
    bf16*  P    = (bf16*)(ws + (72u << 20));     // 33 MB [4][2048][LDP]
    float* lsum = (float*)(ws + (108u << 20));   // 32 KB [8192]

    prep<<<dim3(8192 + 3072 + 1), dim3(256), 0, stream>>>(
        x, wq, wk, wv, xb, Wt, lsum);

    // Q,K (256 blocks, big core) then Vt (512 blocks, small core 2/CU).
    proj_qk<<<dim3(256), dim3(512), 0, stream>>>(xb, Wt, Q, Kb);
    proj_v<<<dim3(512), dim3(256), 0, stream>>>(xb, Wt, Vt);

    // P' = exp(Q @ K^T / 32), row sums -> lsum (big core, control)
    gemm_scores8<<<dim3(256), dim3(512), 0, stream>>>(Q, Kb, P, lsum);

    // out = (P' @ Vt^T) / l (small core, 512 blocks, 2 blocks/CU)
    gemm_pv_sm<<<dim3(512), dim3(256), 0, stream>>>(P, Vt, out, lsum);
}

// Round 8
// 222.933 us; speedup vs baseline: 1.0552x; 1.0552x over previous
//
#include <hip/hip_runtime.h>
#include <cstdint>
#include <cstddef>

typedef __bf16 bf16;
typedef __bf16 bf16x4 __attribute__((ext_vector_type(4)));
typedef __bf16 bf16x8 __attribute__((ext_vector_type(8)));
typedef float  f32x4  __attribute__((ext_vector_type(4)));

#define BATCH 4
#define SEQ   2048
#define DIM   1024
#define LDP   2112   // padded leading dim for P and Vt

// RNE float -> bf16
__device__ __forceinline__ bf16 to_bf16(float f) {
    unsigned u = __builtin_bit_cast(unsigned, f);
    u += 0x7fffu + ((u >> 16) & 1u);
    unsigned short h = (unsigned short)(u >> 16);
    return __builtin_bit_cast(bf16, h);
}

// async global->LDS, 16B per lane. LDS base must be wave-uniform; HW adds lane*16.
__device__ __forceinline__ void load16_lds(const bf16* g, bf16* l) {
    __builtin_amdgcn_global_load_lds(
        (__attribute__((address_space(1))) void*)(g),
        (__attribute__((address_space(3))) void*)(l),
        16, 0, 0);
}

#define BARRIER() do { asm volatile("" ::: "memory"); \
                       __builtin_amdgcn_s_barrier();  \
                       asm volatile("" ::: "memory"); } while (0)
#define LGKM0()   asm volatile("s_waitcnt lgkmcnt(0)" ::: "memory")
#define VM0()     asm volatile("s_waitcnt vmcnt(0)" ::: "memory")
#define VM6()     asm volatile("s_waitcnt vmcnt(6)" ::: "memory")

// ---------------------------------------------------------------------------
// r8 theory: all prior cores drained vmcnt to 0 every K-tile (the T4
// anti-pattern); three different sync structures all plateaued at ~24-29%
// MfmaUtil, and 2-blocks/CU TLP (r7) did NOT help -> the stall is the
// synchronous drain of just-issued staging loads, not per-wave latency.
// gemm_p3_core: 3-deep LDS pipeline, stage tile t+2 during tile t, tile-end
// wait = vmcnt(6) (T(t+1)'s 6 loads retired, T(t+2)'s 6 stay in flight).
// vmcnt(0) only at the tail. pv/proj_v use it; scores/proj_qk stay on the
// big core as controls.
// Chunk swizzle everywhere: LDS[row][p] = global[row][p ^ (row&7)] via
// pre-swizzled global source; readers use pk = (c ^ (row&7))*8. Conflicts=0.
// ---------------------------------------------------------------------------

// stage one half-tile: 128 rows x 64 k of one matrix (2 gload_lds / thread).
__device__ __forceinline__ void stage_half(
    const bf16* __restrict__ srcRow0, int ld, int k0, bf16* dstHalfBase)
{
    const int tid  = threadIdx.x;
    const int wave = tid >> 6;
    const int lane = tid & 63;
    const int rg   = lane >> 3;                 // row within 8-row group
    const int scoff = ((lane & 7) ^ rg) * 8;    // pre-swizzled global chunk
#pragma unroll
    for (int j = 0; j < 2; ++j) {
        const int r = wave * 16 + j * 8;        // wave-uniform LDS row base
        load16_lds(srcRow0 + (size_t)(r + rg) * ld + k0 + scoff,
                   dstHalfBase + r * 64);
    }
}

// ---- 256x256 tile big core (control): 8 waves 2Mx4N, 128 KB LDS --------
__device__ __forceinline__ void gemm_big_core(
    const bf16* __restrict__ Ablk, const bf16* __restrict__ Bblk,
    int K, int lda, int ldb, bf16* As, bf16* Bs, f32x4 acc[8][4])
{
    const int tid  = threadIdx.x;
    const int lane = tid & 63;
    const int wave = tid >> 6;
    const int wr   = wave >> 2;          // 0..1 (M)
    const int wc   = wave & 3;           // 0..3 (N)
    const int r16  = lane & 15;
    const int g    = lane >> 4;
    const int r7   = r16 & 7;
    const int pk0  = ((g) ^ r7) * 8;
    const int pk1  = ((4 + g) ^ r7) * 8;
    const int arow = (wr * 128 + r16) * 64;
    const int brow = (wc * 64 + r16) * 64;
    const int NT   = K >> 6;

    stage_half(Bblk, ldb, 0, Bs);
    stage_half(Bblk + (size_t)128 * ldb, ldb, 0, Bs + 8192);
    stage_half(Ablk, lda, 0, As);
    stage_half(Ablk + (size_t)128 * lda, lda, 0, As + 8192);
    VM0();
    BARRIER();

#pragma unroll 2
    for (int t = 0; t < NT; ++t) {
        bf16* Ac = As + (t & 1) * 16384;
        bf16* Bc = Bs + (t & 1) * 16384;
        bf16* An = As + ((t + 1) & 1) * 16384;
        bf16* Bn = Bs + ((t + 1) & 1) * 16384;
        const int k1 = (t + 1) << 6;

        bf16x8 b[4][2], a[4][2], a2[4][2];
#pragma unroll
        for (int n = 0; n < 4; ++n) {
            b[n][0] = *(const bf16x8*)(Bc + brow + n * 1024 + pk0);
            b[n][1] = *(const bf16x8*)(Bc + brow + n * 1024 + pk1);
        }
#pragma unroll
        for (int m = 0; m < 4; ++m) {
            a[m][0] = *(const bf16x8*)(Ac + arow + m * 1024 + pk0);
            a[m][1] = *(const bf16x8*)(Ac + arow + m * 1024 + pk1);
        }
        if (t + 1 < NT) {
            stage_half(Bblk, ldb, k1, Bn);
            stage_half(Bblk + (size_t)128 * ldb, ldb, k1, Bn + 8192);
            stage_half(Ablk, lda, k1, An);
            stage_half(Ablk + (size_t)128 * lda, lda, k1, An + 8192);
        }
#pragma unroll
        for (int m = 0; m < 4; ++m)
#pragma unroll
            for (int n = 0; n < 4; ++n)
#pragma unroll
                for (int ks = 0; ks < 2; ++ks)
                    acc[m][n] = __builtin_amdgcn_mfma_f32_16x16x32_bf16(
                        a[m][ks], b[n][ks], acc[m][n], 0, 0, 0);
#pragma unroll
        for (int m = 0; m < 4; ++m) {
            a2[m][0] = *(const bf16x8*)(Ac + arow + 4096 + m * 1024 + pk0);
            a2[m][1] = *(const bf16x8*)(Ac + arow + 4096 + m * 1024 + pk1);
        }
#pragma unroll
        for (int m = 0; m < 4; ++m)
#pragma unroll
            for (int n = 0; n < 4; ++n)
#pragma unroll
                for (int ks = 0; ks < 2; ++ks)
                    acc[4 + m][n] = __builtin_amdgcn_mfma_f32_16x16x32_bf16(
                        a2[m][ks], b[n][ks], acc[4 + m][n], 0, 0, 0);

        LGKM0();
        if (t + 1 < NT) VM0();
        BARRIER();
    }
}

// ---- NEW: 256x128 tile, BK=64, 3-deep pipelined core (counted vmcnt) ----
// 8 waves 4Mx2N, per-wave 64x64, acc[4][4]. LDS: A 3x32KB + B 3x16KB = 144KB.
// Per tile: 6 gload_lds/thread (A 2 halves + B 1 half), 16 ds_read_b128/wave,
// 32 MFMA/wave. Steady state: stage T(t+2), wait vmcnt(6) at tile end (T(t+1)
// resident, T(t+2)'s 6 loads stay in flight across the barrier).
// Race-free: slot (t+2)%3's last reads were in tile t-1, drained by that
// tile's LGKM0+BARRIER. vmcnt retires in issue order -> vmcnt(6) == all but
// the 6 just-issued are complete.
__device__ __forceinline__ void gemm_p3_core(
    const bf16* __restrict__ Ablk, const bf16* __restrict__ Bblk,
    int K, int lda, int ldb, bf16* As, bf16* Bs, f32x4 acc[4][4])
{
    const int tid  = threadIdx.x;
    const int lane = tid & 63;
    const int wave = tid >> 6;
    const int wr   = wave >> 1;          // 0..3 (M)
    const int wc   = wave & 1;           // 0..1 (N)
    const int r16  = lane & 15;
    const int g    = lane >> 4;
    const int r7   = r16 & 7;
    const int pk0  = ((g) ^ r7) * 8;
    const int pk1  = ((4 + g) ^ r7) * 8;
    const int arow = (wr * 64 + r16) * 64;
    const int brow = (wc * 64 + r16) * 64;
    const int NT   = K >> 6;

    // prologue: stage T0 -> slot0, T1 -> slot1 (12 loads), then vmcnt(6):
    // T0 resident, T1's 6 in flight.
    stage_half(Ablk, lda, 0, As);
    stage_half(Ablk + (size_t)128 * lda, lda, 0, As + 8192);
    stage_half(Bblk, ldb, 0, Bs);
    stage_half(Ablk, lda, 64, As + 16384);
    stage_half(Ablk + (size_t)128 * lda, lda, 64, As + 16384 + 8192);
    stage_half(Bblk, ldb, 64, Bs + 8192);
    VM6();
    BARRIER();

    int c0 = 0, c2 = 2;                  // current slot, slot for T(t+2)
    for (int t = 0; t < NT; ++t) {
        bf16* Ac = As + c0 * 16384;
        bf16* Bc = Bs + c0 * 8192;

        bf16x8 a[4][2], b[4][2];
#pragma unroll
        for (int n = 0; n < 4; ++n) {
            b[n][0] = *(const bf16x8*)(Bc + brow + n * 1024 + pk0);
            b[n][1] = *(const bf16x8*)(Bc + brow + n * 1024 + pk1);
        }
#pragma unroll
        for (int m = 0; m < 4; ++m) {
            a[m][0] = *(const bf16x8*)(Ac + arow + m * 1024 + pk0);
            a[m][1] = *(const bf16x8*)(Ac + arow + m * 1024 + pk1);
        }
        if (t + 2 < NT) {
            const int k2 = (t + 2) << 6;
            bf16* An = As + c2 * 16384;
            bf16* Bn = Bs + c2 * 8192;
            stage_half(Ablk, lda, k2, An);
            stage_half(Ablk + (size_t)128 * lda, lda, k2, An + 8192);
            stage_half(Bblk, ldb, k2, Bn);
        }
#pragma unroll
        for (int m = 0; m < 4; ++m)
#pragma unroll
            for (int n = 0; n < 4; ++n)
#pragma unroll
                for (int ks = 0; ks < 2; ++ks)
                    acc[m][n] = __builtin_amdgcn_mfma_f32_16x16x32_bf16(
                        a[m][ks], b[n][ks], acc[m][n], 0, 0, 0);

        LGKM0();                          // cur-slot reads retired
        if (t + 1 < NT) {
            if (t + 2 < NT) { VM6(); } else { VM0(); }   // counted, not 0
        }
        BARRIER();
        c0 = (c0 == 2) ? 0 : c0 + 1;
        c2 = (c2 == 2) ? 0 : c2 + 1;
    }
}

// shared bf16 C-writer for the 256^2 core
__device__ __forceinline__ void write_c256(
    bf16* __restrict__ Cb, int ldc, const f32x4 acc[8][4])
{
    const int lane = threadIdx.x & 63;
    const int wave = threadIdx.x >> 6;
    const int wr = wave >> 2, wc = wave & 3;
    const int r16 = lane & 15, g = lane >> 4;
    const int row0 = wr * 128 + g * 4;
    const int col0 = wc * 64 + r16;
#pragma unroll
    for (int m = 0; m < 8; ++m)
#pragma unroll
        for (int n = 0; n < 4; ++n)
#pragma unroll
            for (int rr = 0; rr < 4; ++rr)
                Cb[(size_t)(row0 + m * 16 + rr) * ldc + col0 + n * 16] =
                    to_bf16(acc[m][n][rr]);
}

// ---------------------------------------------------------------------------
// proj_qk (big core, CONTROL): 256 blocks -> Q,K = X @ W{q,k}T^T. XCD-rect.
// ---------------------------------------------------------------------------
__global__ __launch_bounds__(512, 2) void proj_qk(
    const bf16* __restrict__ xb, const bf16* __restrict__ Wt,
    bf16* __restrict__ Q, bf16* __restrict__ Kb)
{
    __shared__ bf16 As[32768];
    __shared__ bf16 Bs[32768];
    f32x4 acc[8][4] = {};

    const int p = blockIdx.x;
    const int x = p & 7, s = p >> 3;
    const int my = x * 4 + (s >> 3);
    const int j  = s & 7;
    const bf16* Ab = xb + (size_t)my * 256 * DIM;
    const bf16* Bb = Wt + (size_t)((j >> 2) ? DIM * DIM : 0)
                        + (size_t)(j & 3) * 256 * DIM;
    bf16* dst = (j >> 2) ? Kb : Q;
    bf16* Cb = dst + (size_t)my * 256 * DIM + (size_t)(j & 3) * 256;

    gemm_big_core(Ab, Bb, DIM, DIM, DIM, As, Bs, acc);
    write_c256(Cb, DIM, acc);
}

// ---------------------------------------------------------------------------
// proj_v (NEW p3 core): 256 blocks -> Vt[b] = WvT @ X[b]^T, 256x128 tiles.
// XCD: bz = x&3, vx-half by x>>2 -> xb panels XCD-local.
// ---------------------------------------------------------------------------
__global__ __launch_bounds__(512, 2) void proj_v(
    const bf16* __restrict__ xb, const bf16* __restrict__ Wt,
    bf16* __restrict__ Vt)
{
    __shared__ bf16 As[49152];   // 3 x 16384 (96 KB)
    __shared__ bf16 Bs[24576];   // 3 x 8192  (48 KB)
    f32x4 acc[4][4] = {};

    const int p = blockIdx.x;
    const int x = p & 7, s = p >> 3;
    const int bz = x & 3;
    const int vx = (x >> 2) * 8 + (s & 7);   // 0..15 (128-col groups)
    const int vy = s >> 3;                   // 0..3  (256-row groups)
    const bf16* Ab = Wt + (size_t)2 * DIM * DIM + (size_t)vy * 256 * DIM;
    const bf16* Bb = xb + (size_t)bz * SEQ * DIM + (size_t)vx * 128 * DIM;
    bf16* Cb = Vt + (size_t)bz * DIM * LDP + (size_t)vy * 256 * LDP
                  + (size_t)vx * 128;

    gemm_p3_core(Ab, Bb, DIM, DIM, DIM, As, Bs, acc);

    const int lane = threadIdx.x & 63;
    const int wave = threadIdx.x >> 6;
    const int wr = wave >> 1, wc = wave & 1;
    const int r16 = lane & 15, g = lane >> 4;
    const int row0 = wr * 64 + g * 4;
    const int col0 = wc * 64 + r16;
#pragma unroll
    for (int m = 0; m < 4; ++m)
#pragma unroll
        for (int n = 0; n < 4; ++n)
#pragma unroll
            for (int rr = 0; rr < 4; ++rr)
                Cb[(size_t)(row0 + m * 16 + rr) * LDP + col0 + n * 16] =
                    to_bf16(acc[m][n][rr]);
}

// ---------------------------------------------------------------------------
// scores (big core, CONTROL): P' = exp((Q @ K^T)/32), row sums via atomics.
// 256 blocks, XCD-rect swizzle.
// ---------------------------------------------------------------------------
__global__ __launch_bounds__(512, 2) void gemm_scores8(
    const bf16* __restrict__ Qm, const bf16* __restrict__ Kb,
    bf16* __restrict__ P, float* __restrict__ lsum)
{
    __shared__ bf16 As[32768];
    __shared__ bf16 Bs[32768];
    f32x4 acc[8][4] = {};

    const int p = blockIdx.x;
    const int x = p & 7, s = p >> 3;
    const int bz = x & 3;
    const int by = (x >> 2) * 4 + (s >> 3);
    const int bx = s & 7;
    const bf16* Ab = Qm + (size_t)bz * SEQ * DIM + (size_t)by * 256 * DIM;
    const bf16* Bb = Kb + (size_t)bz * SEQ * DIM + (size_t)bx * 256 * DIM;
    gemm_big_core(Ab, Bb, DIM, DIM, DIM, As, Bs, acc);

    bf16* Cb  = P + (size_t)bz * SEQ * LDP;
    float* ls = lsum + (size_t)bz * SEQ;
    const int lane = threadIdx.x & 63;
    const int wave = threadIdx.x >> 6;
    const int wr = wave >> 2, wc = wave & 3;
    const int r16 = lane & 15, g = lane >> 4;
    const int rowB = by * 256 + wr * 128 + g * 4;
    const int colB = bx * 256 + wc * 64 + r16;
#pragma unroll
    for (int m = 0; m < 8; ++m)
#pragma unroll
        for (int rr = 0; rr < 4; ++rr) {
            float sum = 0.0f;
#pragma unroll
            for (int n = 0; n < 4; ++n) {
                const float e = __expf(acc[m][n][rr] * 0.03125f);
                sum += e;
                Cb[(size_t)(rowB + m * 16 + rr) * LDP + colB + n * 16] = to_bf16(e);
            }
            sum += __shfl_xor(sum, 1);
            sum += __shfl_xor(sum, 2);
            sum += __shfl_xor(sum, 4);
            sum += __shfl_xor(sum, 8);
            if (r16 == 0)
                atomicAdd(ls + rowB + m * 16 + rr, sum);
        }
}

// ---------------------------------------------------------------------------
// PV (NEW p3 core): out = (P' @ Vt^T) / l, fp32. 256 blocks (8 by x 8 bx x
// 4 bz), 256x128 tiles, K = SEQ (NT=32). XCD keeps P panels XCD-exclusive.
// ---------------------------------------------------------------------------
__global__ __launch_bounds__(512, 2) void gemm_pv_p3(
    const bf16* __restrict__ P, const bf16* __restrict__ Vt,
    float* __restrict__ C, const float* __restrict__ lsum)
{
    __shared__ bf16 As[49152];   // 3 x 16384 (96 KB)
    __shared__ bf16 Bs[24576];   // 3 x 8192  (48 KB)
    f32x4 acc[4][4] = {};

    const int p = blockIdx.x;
    const int x = p & 7, s = p >> 3;
    const int bz = x & 3;
    const int by = (x >> 2) * 4 + (s >> 3);  // 0..7 (256-row P panels)
    const int bx = s & 7;                    // 0..7 (128-col out panels)
    const bf16* Ab = P  + (size_t)bz * SEQ * LDP + (size_t)by * 256 * LDP;
    const bf16* Bb = Vt + (size_t)bz * DIM * LDP + (size_t)bx * 128 * LDP;
    gemm_p3_core(Ab, Bb, SEQ, LDP, LDP, As, Bs, acc);

    float* Cb = C + (size_t)bz * SEQ * DIM;
    const float* ls = lsum + (size_t)bz * SEQ;
    const int lane = threadIdx.x & 63;
    const int wave = threadIdx.x >> 6;
    const int wr = wave >> 1, wc = wave & 1;
    const int r16 = lane & 15, g = lane >> 4;
    const int row0 = by * 256 + wr * 64 + g * 4;
    const int col0 = bx * 128 + wc * 64 + r16;
#pragma unroll
    for (int m = 0; m < 4; ++m)
#pragma unroll
        for (int rr = 0; rr < 4; ++rr) {
            const int row = row0 + m * 16 + rr;
            const float inv = __builtin_amdgcn_rcpf(ls[row]);
#pragma unroll
            for (int n = 0; n < 4; ++n)
                Cb[(size_t)row * DIM + col0 + n * 16] = acc[m][n][rr] * inv;
        }
}

// ---------------------------------------------------------------------------
// Fused prep: blocks [0,8192) cast x fp32->bf16; blocks [8192,11264) transpose
// + cast weights; block 11264 zeroes lsum. All branches block-uniform.
// ---------------------------------------------------------------------------
__global__ __launch_bounds__(256) void prep(
    const float* __restrict__ x,  const float* __restrict__ wq,
    const float* __restrict__ wk, const float* __restrict__ wv,
    bf16* __restrict__ xb, bf16* __restrict__ Wt, float* __restrict__ lsum)
{
    __shared__ float tile[32][33];
    const int b = blockIdx.x;
    const int tid = threadIdx.x;
    if (b < 8192) {
        const size_t i = ((size_t)b * 256 + tid) * 4;
        const float4 v = *(const float4*)(x + i);
        bf16x4 o = { to_bf16(v.x), to_bf16(v.y), to_bf16(v.z), to_bf16(v.w) };
        *(bf16x4*)(xb + i) = o;
    } else if (b < 8192 + 3072) {
        const int t   = b - 8192;
        const int sel = t >> 10;
        const int n0  = (t & 31) * 32;
        const int k0  = ((t >> 5) & 31) * 32;
        const float* w = (sel == 0) ? wq : (sel == 1) ? wk : wv;
        const int tx = tid & 31, ty = tid >> 5;
#pragma unroll
        for (int j = 0; j < 32; j += 8)
            tile[ty + j][tx] = w[(size_t)(k0 + ty + j) * 1024 + n0 + tx];
        __syncthreads();
        bf16* dst = Wt + (size_t)sel * 1024 * 1024;
#pragma unroll
        for (int j = 0; j < 32; j += 8)
            dst[(size_t)(n0 + ty + j) * 1024 + k0 + tx] = to_bf16(tile[tx][ty + j]);
    } else {
#pragma unroll
        for (int i = 0; i < 32; ++i)
            lsum[i * 256 + tid] = 0.0f;
    }
}

// ---------------------------------------------------------------------------
extern "C" void kernel_launch(void* const* d_in, const int* in_sizes, int n_in,
                              void* d_out, int out_size, void* d_ws, size_t ws_size,
                              hipStream_t stream)
{
    const float* x  = (const float*)d_in[0];
    const float* wq = (const float*)d_in[1];
    const float* wk = (const float*)d_in[2];
    const float* wv = (const float*)d_in[3];
    float* out = (float*)d_out;
    char* ws = (char*)d_ws;

    // workspace layout (bytes)
    bf16*  xb   = (bf16*)(ws);                   // 16 MB [8192,1024]
    bf16*  Wt   = (bf16*)(ws + (16u << 20));     //  6 MB [3072,1024] (WqT|WkT|WvT)
    bf16*  Q    = (bf16*)(ws + (22u << 20));     // 16 MB [8192,1024]
    bf16*  Kb   = (bf16*)(ws + (38u << 20));     // 16 MB [8192,1024]
    bf16*  Vt   = (bf16*)(ws + (54u << 20));     // 17 MB [4][1024][LDP]
    bf16*  P    = (bf16*)(ws + (72u << 20));     // 33 MB [4][2048][LDP]
    float* lsum = (float*)(ws + (108u << 20));   // 32 KB [8192]

    prep<<<dim3(8192 + 3072 + 1), dim3(256), 0, stream>>>(
        x, wq, wk, wv, xb, Wt, lsum);

    // Q,K (big core, control) then Vt (NEW 3-deep pipelined core).
    proj_qk<<<dim3(256), dim3(512), 0, stream>>>(xb, Wt, Q, Kb);
    proj_v<<<dim3(256), dim3(512), 0, stream>>>(xb, Wt, Vt);

    // P' = exp(Q @ K^T / 32), row sums -> lsum (big core, control)
    gemm_scores8<<<dim3(256), dim3(512), 0, stream>>>(Q, Kb, P, lsum);

    // out = (P' @ Vt^T) / l (NEW 3-deep pipelined core, counted vmcnt)
    gemm_pv_p3<<<dim3(256), dim3(512), 0, stream>>>(P, Vt, out, lsum);
}